// Round 6
// baseline (225.340 us; speedup 1.0000x reference)
//
#include <hip/hip_runtime.h>
#include <math.h>

// Problem constants: B=1024, N=200, E=128, fp32.
constexpr int Bc = 1024;
constexpr int Nc = 200;
constexpr int Ec = 128;

// R6: R5 (nt loads + value-pin) dropped dist_phase below the 61us harness
// fills. Remaining gap vs the 33us streaming floor is the burst-idle duty
// cycle: each block loads 10x16B, waits vmcnt(0), computes ~1000cy with zero
// loads outstanding, exits. Fix: persistent per-batch block (1024 blocks,
// uniform 5 tiles), register double-buffer: issue tile p+1's nt-loads before
// computing tile p. Ordering: loads can't sink past the memory-clobber asm;
// compute can't hoist above the volatile value-pin (volatile asms keep
// program order). Compiler then emits a COUNTED vmcnt (wait cur while nxt in
// flight) - continuous ~10 outstanding loads per wave.
// __launch_bounds__(256,2): allocator cap 128 VGPR (empirical: cap=256/minw;
// (256,4) capped at 64 and forced the R3 burst-split). Expect ~120 VGPR ->
// 4 waves/SIMD, 16 waves/CU.
constexpr int ROWS   = 5;                  // rows per 32-lane group per tile
constexpr int GROUPS = 8;                  // 256 threads / 32
constexpr int TILES  = 5;                  // 5 tiles x 40 rows = 200

typedef float v4f __attribute__((ext_vector_type(4)));

__global__ __launch_bounds__(256, 2) void dist_phase(
    const float* __restrict__ q,      // (B,E)
    const float* __restrict__ q_p,    // (B,E)
    const float* __restrict__ m,      // (B,N,E)
    const float* __restrict__ m_c,    // (B,N,E)
    const float* __restrict__ A1,     // (E)
    const float* __restrict__ A2,     // (E)
    const float* __restrict__ biases, // (B,N)
    const float* __restrict__ mask,   // (B,N)
    float* __restrict__ xs_ws,        // (B,N) softmax arguments -> workspace
    float* __restrict__ out)          // (B,N) out_dist*mask (scaled by k2)
{
    const int b    = blockIdx.x;     // batch
    const int tid  = threadIdx.x;
    const int hw   = tid >> 5;       // group id 0..7
    const int lane = tid & 31;
    const int e0   = lane * 4;

    const v4f qv  = *reinterpret_cast<const v4f*>(q   + (size_t)b * Ec + e0);
    const v4f qpv = *reinterpret_cast<const v4f*>(q_p + (size_t)b * Ec + e0);
    const v4f a1v = *reinterpret_cast<const v4f*>(A1  + e0);
    const v4f a2v = *reinterpret_cast<const v4f*>(A2  + e0);

    const float* mb  = m   + (size_t)b * Nc * Ec;
    const float* mcb = m_c + (size_t)b * Nc * Ec;

    v4f mv[2][ROWS], mcv[2][ROWS];

    // Prologue: tile 0 loads.
    {
        const int n0 = hw * ROWS;
#pragma unroll
        for (int r = 0; r < ROWS; ++r) {
            mv[0][r]  = __builtin_nontemporal_load(
                reinterpret_cast<const v4f*>(mb  + (size_t)(n0 + r) * Ec + e0));
            mcv[0][r] = __builtin_nontemporal_load(
                reinterpret_cast<const v4f*>(mcb + (size_t)(n0 + r) * Ec + e0));
        }
    }

#pragma unroll
    for (int p = 0; p < TILES; ++p) {
        const int cur = p & 1;         // compile-time after full unroll
        const int nxt = cur ^ 1;

        // Prefetch next tile (nt): issued BEFORE current tile's compute.
        if (p + 1 < TILES) {
            const int n1 = (p + 1) * (GROUPS * ROWS) + hw * ROWS;
#pragma unroll
            for (int r = 0; r < ROWS; ++r) {
                mv[nxt][r]  = __builtin_nontemporal_load(
                    reinterpret_cast<const v4f*>(mb  + (size_t)(n1 + r) * Ec + e0));
                mcv[nxt][r] = __builtin_nontemporal_load(
                    reinterpret_cast<const v4f*>(mcb + (size_t)(n1 + r) * Ec + e0));
            }
        }
        // Memory clobber: prefetch loads cannot sink below this point.
        asm volatile("" ::: "memory");
        // Value-pin current tile: compute below depends on these outputs and
        // volatile-asm order keeps it below the clobber -> counted vmcnt wait
        // for cur only, nxt stays in flight.
        asm volatile("" : "+v"(mv[cur][0]), "+v"(mv[cur][1]), "+v"(mv[cur][2]),
                          "+v"(mv[cur][3]), "+v"(mv[cur][4]),
                          "+v"(mcv[cur][0]), "+v"(mcv[cur][1]), "+v"(mcv[cur][2]),
                          "+v"(mcv[cur][3]), "+v"(mcv[cur][4]));

        float s_att[ROWS], s_out[ROWS];
#pragma unroll
        for (int r = 0; r < ROWS; ++r) {
            float sa = 0.f, so = 0.f;
#pragma unroll
            for (int c = 0; c < 4; ++c) {
                float t1 = (qv[c]  - mv[cur][r][c])  * a1v[c];  sa = fmaf(t1, t1, sa);
                float t2 = (qpv[c] - mv[cur][r][c])  * a2v[c];  sa = fmaf(t2, t2, sa);
                float u1 = (qv[c]  - mcv[cur][r][c]) * a1v[c];  so = fmaf(u1, u1, so);
                float u2 = (qpv[c] - mcv[cur][r][c]) * a2v[c];  so = fmaf(u2, u2, so);
            }
            s_att[r] = sa;
            s_out[r] = so;
        }

        // 10 interleaved shuffle-reduce chains (xor <=16 stays in the 32-lane half).
#pragma unroll
        for (int off = 16; off > 0; off >>= 1) {
#pragma unroll
            for (int r = 0; r < ROWS; ++r) {
                s_att[r] += __shfl_xor(s_att[r], off);
                s_out[r] += __shfl_xor(s_out[r], off);
            }
        }

        if (lane == 0) {
            const int n0 = p * (GROUPS * ROWS) + hw * ROWS;
#pragma unroll
            for (int r = 0; r < ROWS; ++r) {
                const int n = n0 + r;
                const float bb = biases[(size_t)b * Nc + n];
                const float mk = mask[(size_t)b * Nc + n];
                // att_dist = d1 + bias + d2 + bias = s_att + 2*bias
                xs_ws[(size_t)b * Nc + n] = -(s_att[r] + 2.f * bb) * mk;
                out  [(size_t)b * Nc + n] =  (s_out[r] + 2.f * bb) * mk;
            }
        }
    }
}

// One 256-thread block per batch: softmax over the 200 entries, scale os.
__global__ __launch_bounds__(256, 4) void softmax_phase(
    const float* __restrict__ xs_ws,  // (B,N)
    float* __restrict__ out)          // (B,N) in: os, out: os * softmax
{
    const int b   = blockIdx.x;
    const int tid = threadIdx.x;

    __shared__ float red_s[8];  // 4 max + 4 sum

    const float x  = (tid < Nc) ? xs_ws[(size_t)b * Nc + tid] : -INFINITY;
    const float os = (tid < Nc) ? out  [(size_t)b * Nc + tid] : 0.f;

    // max
    float wmax = x;
#pragma unroll
    for (int off = 32; off > 0; off >>= 1)
        wmax = fmaxf(wmax, __shfl_xor(wmax, off));
    if ((tid & 63) == 0) red_s[tid >> 6] = wmax;
    __syncthreads();
    const float gmax = fmaxf(fmaxf(red_s[0], red_s[1]), fmaxf(red_s[2], red_s[3]));

    // sum of exp
    const float ex = (tid < Nc) ? expf(x - gmax) : 0.f;
    float wsum = ex;
#pragma unroll
    for (int off = 32; off > 0; off >>= 1)
        wsum += __shfl_xor(wsum, off);
    if ((tid & 63) == 0) red_s[4 + (tid >> 6)] = wsum;
    __syncthreads();
    const float gsum = (red_s[4] + red_s[5]) + (red_s[6] + red_s[7]);

    if (tid < Nc) {
        out[(size_t)b * Nc + tid] = os * (ex / gsum);
    }
}

extern "C" void kernel_launch(void* const* d_in, const int* in_sizes, int n_in,
                              void* d_out, int out_size, void* d_ws, size_t ws_size,
                              hipStream_t stream) {
    const float* q      = (const float*)d_in[0];
    const float* q_p    = (const float*)d_in[1];
    const float* m      = (const float*)d_in[2];
    const float* m_c    = (const float*)d_in[3];
    const float* A1     = (const float*)d_in[4];
    const float* A2     = (const float*)d_in[5];
    const float* biases = (const float*)d_in[6];
    const float* mask   = (const float*)d_in[7];
    float* out   = (float*)d_out;
    float* xs_ws = (float*)d_ws;     // needs B*N*4 = 800 KB of workspace

    dist_phase<<<Bc, 256, 0, stream>>>(q, q_p, m, m_c, A1, A2, biases, mask,
                                       xs_ws, out);
    softmax_phase<<<Bc, 256, 0, stream>>>(xs_ws, out);
}